// Round 3
// baseline (1128.609 us; speedup 1.0000x reference)
//
#include <hip/hip_runtime.h>

// Flux2 double-stream attention block, bf16 MFMA pipeline, f32 final output.
// Stages: cvt(f32->bf16) -> QKV GEMM -> RMSnorm+RoPE(+V^T) -> flash attn -> out GEMM.
// ws layout (bytes):
//   [0,           22020096)  A_in bf16 [3584][3072]   (enc rows 0..511, img 512..)   } later aliased by V^T [24][128][3584]
//   [22020096,   135266304)  Wq bf16: img [9216][3072] then enc                      } later aliased by attn_out [3584][3072]
//   [135266304,  173015040)  Wo bf16: img [3072][3072] then enc
//   [173015040,  239075328)  qkv bf16 [3584][9216] (q|k|v thirds; normed+roped in place)
// peak ws = 239,075,328 B.

typedef unsigned short u16;
typedef __attribute__((ext_vector_type(2))) unsigned short u16x2;
typedef __attribute__((ext_vector_type(4))) unsigned short u16x4;
typedef __attribute__((ext_vector_type(8))) unsigned short u16x8;
typedef __attribute__((ext_vector_type(8))) short bf16x8;
typedef __attribute__((ext_vector_type(4))) float f32x4;

#define DEV __device__ __forceinline__

DEV u16 f2bf(float f) {
  unsigned u = __builtin_bit_cast(unsigned, f);
  u = (u + 0x7FFFu + ((u >> 16) & 1u)) >> 16;   // RNE
  return (u16)u;
}
DEV float bf2f(u16 s) { return __builtin_bit_cast(float, (unsigned)s << 16); }

DEV void store_out(u16* p, float v)  { *p = f2bf(v); }
DEV void store_out(float* p, float v) { *p = v; }

#define AS1(p) (const __attribute__((address_space(1))) void*)(p)
#define AS3(p) (__attribute__((address_space(3))) void*)(p)
#define GLL16(g, l) __builtin_amdgcn_global_load_lds(AS1(g), AS3(l), 16, 0, 0)

// ---------------- fp32 -> bf16 convert ----------------
__global__ __launch_bounds__(256) void cvt_kernel(const float* __restrict__ src,
                                                  u16* __restrict__ dst, int n4) {
  int i = blockIdx.x * blockDim.x + threadIdx.x;
  int stride = gridDim.x * blockDim.x;
  for (; i < n4; i += stride) {
    float4 v = reinterpret_cast<const float4*>(src)[i];
    u16x4 o;
    o.x = f2bf(v.x); o.y = f2bf(v.y); o.z = f2bf(v.z); o.w = f2bf(v.w);
    reinterpret_cast<u16x4*>(dst)[i] = o;
  }
}

// ---------------- GEMM: C[M][N] = A[M][K] * B[N][K]^T (+bias) ----------------
// bf16 in; output type OT (bf16 for internal qkv, float for d_out).
// 128x128 tile, BK=64, 4 waves (2x2), each wave 64x64 = 4x4 frags of 16x16x32.
template <typename OT>
__global__ __launch_bounds__(256) void gemm_bt(
    const u16* __restrict__ A,
    const u16* __restrict__ Bimg, const u16* __restrict__ Benc,
    const float* __restrict__ biasImg, const float* __restrict__ biasEnc,
    OT* __restrict__ Cimg, OT* __restrict__ Cenc,
    int N, int K, int split) {
  const int nt = blockIdx.x, mt = blockIdx.y;
  const int m0 = mt * 128, n0 = nt * 128;
  const u16* B = (m0 < split) ? Benc : Bimg;
  const float* bias = (m0 < split) ? biasEnc : biasImg;
  __shared__ u16 lA[128 * 64];
  __shared__ u16 lB[128 * 64];
  const int tid = threadIdx.x, w = tid >> 6, lane = tid & 63;
  const int wm = w >> 1, wn = w & 1;
  f32x4 acc[4][4];
#pragma unroll
  for (int i = 0; i < 4; ++i)
#pragma unroll
    for (int j = 0; j < 4; ++j)
#pragma unroll
      for (int r = 0; r < 4; ++r) acc[i][j][r] = 0.f;

  for (int kb = 0; kb < K; kb += 64) {
    __syncthreads();
#pragma unroll
    for (int j = 0; j < 4; ++j) {
      int base = j * 4096 + w * 1024;          // byte offset in 16KB tile
      int off = base + lane * 16;
      int row = off >> 7;                      // 128 B per row (64 bf16)
      int colb = off & 127;
      GLL16((const char*)A + ((size_t)(m0 + row) * K + kb) * 2 + colb, (char*)lA + base);
      GLL16((const char*)B + ((size_t)(n0 + row) * K + kb) * 2 + colb, (char*)lB + base);
    }
    __syncthreads();
#pragma unroll
    for (int ks = 0; ks < 2; ++ks) {
      bf16x8 af[4], bfr[4];
#pragma unroll
      for (int i = 0; i < 4; ++i) {
        af[i]  = *(const bf16x8*)&lA[(wm * 64 + i * 16 + (lane & 15)) * 64 + ks * 32 + ((lane >> 4) << 3)];
        bfr[i] = *(const bf16x8*)&lB[(wn * 64 + i * 16 + (lane & 15)) * 64 + ks * 32 + ((lane >> 4) << 3)];
      }
#pragma unroll
      for (int i = 0; i < 4; ++i)
#pragma unroll
        for (int j = 0; j < 4; ++j)
          acc[i][j] = __builtin_amdgcn_mfma_f32_16x16x32_bf16(af[i], bfr[j], acc[i][j], 0, 0, 0);
    }
  }
  // epilogue: C[row][col], row = m*16 + (lane>>4)*4 + r, col = n*16 + (lane&15)
#pragma unroll
  for (int i = 0; i < 4; ++i) {
    int rbase = m0 + wm * 64 + i * 16 + ((lane >> 4) << 2);
#pragma unroll
    for (int j = 0; j < 4; ++j) {
      int col = n0 + wn * 64 + j * 16 + (lane & 15);
      float bv = bias ? bias[col] : 0.f;
#pragma unroll
      for (int r = 0; r < 4; ++r) {
        int row = rbase + r;
        float v = acc[i][j][r] + bv;
        if (row < split) store_out(&Cenc[(size_t)row * N + col], v);
        else             store_out(&Cimg[(size_t)(row - split) * N + col], v);
      }
    }
  }
}

// ---------------- per-head RMSnorm(q,k) + RoPE(q,k), emit V^T -----------------
// grid (56, 24): 64 seq rows x 1 head per block; wave w owns rows w*16..w*16+15.
// lane l holds d = 2l, 2l+1 (rope pair lives in one lane).
__global__ __launch_bounds__(256) void norm_rope(
    u16* __restrict__ qkv, u16* __restrict__ vt,
    const float* __restrict__ cosT, const float* __restrict__ sinT,
    const float* __restrict__ nqw_img, const float* __restrict__ nkw_img,
    const float* __restrict__ nqw_enc, const float* __restrict__ nkw_enc) {
  const int h = blockIdx.y;
  const int s0 = blockIdx.x * 64;
  const int tid = threadIdx.x, w = tid >> 6, lane = tid & 63;
  const bool enc = (s0 < 512);
  const float* nqw = enc ? nqw_enc : nqw_img;
  const float* nkw = enc ? nkw_enc : nkw_img;
  const float wq0 = nqw[2 * lane], wq1 = nqw[2 * lane + 1];
  const float wk0 = nkw[2 * lane], wk1 = nkw[2 * lane + 1];
  u16x8 va0, va1, vb0, vb1;
#pragma unroll
  for (int r = 0; r < 16; ++r) {
    const int s = s0 + w * 16 + r;
    const size_t rowb = (size_t)s * 9216 + h * 128 + 2 * lane;
    float2 cv = *(const float2*)&cosT[(size_t)s * 128 + 2 * lane];
    float2 sv = *(const float2*)&sinT[(size_t)s * 128 + 2 * lane];
    {  // Q
      u16x2 qu = *(u16x2*)&qkv[rowb];
      float x0 = bf2f(qu.x), x1 = bf2f(qu.y);
      float ss = x0 * x0 + x1 * x1;
#pragma unroll
      for (int d = 1; d < 64; d <<= 1) ss += __shfl_xor(ss, d);
      float rms = rsqrtf(ss * (1.0f / 128.0f) + 1e-5f);
      x0 *= rms * wq0; x1 *= rms * wq1;
      float o0 = x0 * cv.x - x1 * sv.x;
      float o1 = x1 * cv.y + x0 * sv.y;
      u16x2 ou; ou.x = f2bf(o0); ou.y = f2bf(o1);
      *(u16x2*)&qkv[rowb] = ou;
    }
    {  // K
      u16x2 ku = *(u16x2*)&qkv[rowb + 3072];
      float x0 = bf2f(ku.x), x1 = bf2f(ku.y);
      float ss = x0 * x0 + x1 * x1;
#pragma unroll
      for (int d = 1; d < 64; d <<= 1) ss += __shfl_xor(ss, d);
      float rms = rsqrtf(ss * (1.0f / 128.0f) + 1e-5f);
      x0 *= rms * wk0; x1 *= rms * wk1;
      float o0 = x0 * cv.x - x1 * sv.x;
      float o1 = x1 * cv.y + x0 * sv.y;
      u16x2 ou; ou.x = f2bf(o0); ou.y = f2bf(o1);
      *(u16x2*)&qkv[rowb + 3072] = ou;
    }
    {  // V -> registers for transposed store
      u16x2 vu = *(u16x2*)&qkv[rowb + 6144];
      if (r < 8) { va0[r] = vu.x; vb0[r] = vu.y; }
      else       { va1[r - 8] = vu.x; vb1[r - 8] = vu.y; }
    }
  }
  // V^T[h][d][s]: lane writes its two d-rows, 16 contiguous s each (2x16B stores/row)
  const size_t vbase = (size_t)h * 128 * 3584 + (size_t)(2 * lane) * 3584 + s0 + w * 16;
  *(u16x8*)&vt[vbase]            = va0;
  *(u16x8*)&vt[vbase + 8]        = va1;
  *(u16x8*)&vt[vbase + 3584]     = vb0;
  *(u16x8*)&vt[vbase + 3584 + 8] = vb1;
}

// ---------------- flash attention ----------------
// grid (28, 24): q-tile of 128 rows x head. 4 waves, each 32 q-rows.
// K tile [64][128] and V^T tile [128][64] staged to LDS with XOR-swizzled
// global source + linear global_load_lds dest (rule #21); reads apply same XOR.
__global__ __launch_bounds__(256) void attn_kernel(
    const u16* __restrict__ qkv, const u16* __restrict__ vt,
    u16* __restrict__ aout) {
  const int h = blockIdx.y, qt = blockIdx.x;
  const int tid = threadIdx.x, w = tid >> 6, lane = tid & 63;
  const int qbase = qt * 128 + w * 32;
  __shared__ u16 Klds[64 * 128];
  __shared__ u16 Vlds[128 * 64];
  __shared__ u16 Plds[4][2048];  // per-wave 32x64 bf16

  bf16x8 aq[2][4];
#pragma unroll
  for (int qg = 0; qg < 2; ++qg) {
    const u16* qp = qkv + (size_t)(qbase + qg * 16 + (lane & 15)) * 9216 + h * 128 + ((lane >> 4) << 3);
#pragma unroll
    for (int ks = 0; ks < 4; ++ks) aq[qg][ks] = *(const bf16x8*)(qp + ks * 32);
  }
  float m_i[2][4], l_i[2][4];
  f32x4 o[2][8];
#pragma unroll
  for (int qg = 0; qg < 2; ++qg) {
#pragma unroll
    for (int r = 0; r < 4; ++r) { m_i[qg][r] = -1e30f; l_i[qg][r] = 0.f; }
#pragma unroll
    for (int dt = 0; dt < 8; ++dt)
#pragma unroll
      for (int r = 0; r < 4; ++r) o[qg][dt][r] = 0.f;
  }
  const float scale = 0.088388347648318447f;  // 1/sqrt(128)
  const size_t vhead = (size_t)h * 128 * 3584;

  for (int kt0 = 0; kt0 < 3584; kt0 += 64) {
    __syncthreads();
#pragma unroll
    for (int j = 0; j < 4; ++j) {  // K tile: 64 rows x 256B
      int base = w * 4096 + j * 1024;
      int off = base + lane * 16;
      int row = off >> 8;
      int src = (off & 255) ^ ((row & 7) << 4);
      GLL16((const char*)(qkv + (size_t)(kt0 + row) * 9216 + 3072 + h * 128) + src, (char*)Klds + base);
    }
#pragma unroll
    for (int j = 0; j < 4; ++j) {  // V^T tile: 128 rows x 128B
      int base = w * 4096 + j * 1024;
      int off = base + lane * 16;
      int d = off >> 7;
      int src = (off & 127) ^ ((d & 7) << 4);
      GLL16((const char*)(vt + vhead + (size_t)d * 3584 + kt0) + src, (char*)Vlds + base);
    }
    __syncthreads();

    // S = Q K^T
    f32x4 sacc[2][4];
#pragma unroll
    for (int qg = 0; qg < 2; ++qg)
#pragma unroll
      for (int kt = 0; kt < 4; ++kt)
#pragma unroll
        for (int r = 0; r < 4; ++r) sacc[qg][kt][r] = 0.f;
#pragma unroll
    for (int kt = 0; kt < 4; ++kt) {
      const int row = kt * 16 + (lane & 15);
      bf16x8 bk[4];
#pragma unroll
      for (int ks = 0; ks < 4; ++ks) {
        int cb = (ks * 32 + ((lane >> 4) << 3)) * 2;
        bk[ks] = *(const bf16x8*)((const char*)Klds + (row * 256 + (cb ^ ((row & 7) << 4))));
      }
#pragma unroll
      for (int qg = 0; qg < 2; ++qg)
#pragma unroll
        for (int ks = 0; ks < 4; ++ks)
          sacc[qg][kt] = __builtin_amdgcn_mfma_f32_16x16x32_bf16(aq[qg][ks], bk[ks], sacc[qg][kt], 0, 0, 0);
    }

    // online softmax (row stats fp32; row lives in 16 consecutive lanes)
#pragma unroll
    for (int qg = 0; qg < 2; ++qg) {
      float alpha[4];
#pragma unroll
      for (int r = 0; r < 4; ++r) {
        float mx = fmaxf(fmaxf(sacc[qg][0][r], sacc[qg][1][r]), fmaxf(sacc[qg][2][r], sacc[qg][3][r]));
#pragma unroll
        for (int d = 1; d < 16; d <<= 1) mx = fmaxf(mx, __shfl_xor(mx, d));
        mx *= scale;
        float mnew = fmaxf(m_i[qg][r], mx);
        alpha[r] = __expf(m_i[qg][r] - mnew);
        m_i[qg][r] = mnew;
      }
      float psum[4] = {0.f, 0.f, 0.f, 0.f};
#pragma unroll
      for (int kt = 0; kt < 4; ++kt) {
        const int col = kt * 16 + (lane & 15);
#pragma unroll
        for (int r = 0; r < 4; ++r) {
          float p = __expf(sacc[qg][kt][r] * scale - m_i[qg][r]);
          psum[r] += p;
          const int prow = qg * 16 + ((lane >> 4) << 2) + r;
          *(u16*)((char*)Plds[w] + ((prow * 128 + col * 2) ^ ((prow & 7) << 4))) = f2bf(p);
        }
      }
#pragma unroll
      for (int r = 0; r < 4; ++r) {
        float ps = psum[r];
#pragma unroll
        for (int d = 1; d < 16; d <<= 1) ps += __shfl_xor(ps, d);
        l_i[qg][r] = l_i[qg][r] * alpha[r] + ps;
        // rescale ONLY row r of the accumulator (per-row alpha)
#pragma unroll
        for (int dt = 0; dt < 8; ++dt) o[qg][dt][r] *= alpha[r];
      }
    }

    // O += P V   (P from per-wave LDS as A-frag; V^T rows are the B-operand)
    bf16x8 pa[2][2];
#pragma unroll
    for (int qg = 0; qg < 2; ++qg) {
      const int prow = qg * 16 + (lane & 15);
#pragma unroll
      for (int ks = 0; ks < 2; ++ks) {
        int cb = (ks * 32 + ((lane >> 4) << 3)) * 2;
        pa[qg][ks] = *(const bf16x8*)((const char*)Plds[w] + ((prow * 128 + cb) ^ ((prow & 7) << 4)));
      }
    }
#pragma unroll
    for (int dt = 0; dt < 8; ++dt) {
      const int vrow = dt * 16 + (lane & 15);
      bf16x8 bv[2];
#pragma unroll
      for (int ks = 0; ks < 2; ++ks) {
        int cb = (ks * 32 + ((lane >> 4) << 3)) * 2;
        bv[ks] = *(const bf16x8*)((const char*)Vlds + ((vrow * 128 + cb) ^ ((vrow & 7) << 4)));
      }
#pragma unroll
      for (int qg = 0; qg < 2; ++qg) {
        o[qg][dt] = __builtin_amdgcn_mfma_f32_16x16x32_bf16(pa[qg][0], bv[0], o[qg][dt], 0, 0, 0);
        o[qg][dt] = __builtin_amdgcn_mfma_f32_16x16x32_bf16(pa[qg][1], bv[1], o[qg][dt], 0, 0, 0);
      }
    }
  }

  // epilogue: O /= l, scatter bf16 to attn_out[s][h*128+d]
#pragma unroll
  for (int qg = 0; qg < 2; ++qg) {
#pragma unroll
    for (int r = 0; r < 4; ++r) {
      const float inv = 1.0f / l_i[qg][r];
      const int s = qbase + qg * 16 + ((lane >> 4) << 2) + r;
#pragma unroll
      for (int dt = 0; dt < 8; ++dt) {
        aout[(size_t)s * 3072 + h * 128 + dt * 16 + (lane & 15)] = f2bf(o[qg][dt][r] * inv);
      }
    }
  }
}

extern "C" void kernel_launch(void* const* d_in, const int* in_sizes, int n_in,
                              void* d_out, int out_size, void* d_ws, size_t ws_size,
                              hipStream_t stream) {
  (void)in_sizes; (void)n_in; (void)out_size; (void)ws_size;
  const float* hs    = (const float*)d_in[0];
  const float* ehs   = (const float*)d_in[1];
  const float* cosT  = (const float*)d_in[2];
  const float* sinT  = (const float*)d_in[3];
  const float* Wqkv  = (const float*)d_in[4];
  const float* Wadd  = (const float*)d_in[5];
  const float* bAdd  = (const float*)d_in[6];
  const float* nqw   = (const float*)d_in[7];
  const float* nkw   = (const float*)d_in[8];
  const float* naqw  = (const float*)d_in[9];
  const float* nakw  = (const float*)d_in[10];
  const float* Wout  = (const float*)d_in[11];
  const float* bout  = (const float*)d_in[12];
  const float* Waddo = (const float*)d_in[13];
  const float* baddo = (const float*)d_in[14];

  char* ws = (char*)d_ws;
  u16* Ain = (u16*)(ws);                       // [3584][3072]
  u16* WqI = (u16*)(ws + 22020096);            // [9216][3072]
  u16* WqE = WqI + (size_t)9216 * 3072;
  u16* WoI = (u16*)(ws + 135266304);           // [3072][3072]
  u16* WoE = WoI + (size_t)3072 * 3072;
  u16* qkv = (u16*)(ws + 173015040);           // [3584][9216]
  u16* vt   = Ain;  // alias: A_in dead after QKV GEMM
  u16* aout = WqI;  // alias: W_qkv dead after QKV GEMM

  cvt_kernel<<<1024, 256, 0, stream>>>(ehs,   Ain,                      512 * 3072 / 4);
  cvt_kernel<<<1024, 256, 0, stream>>>(hs,    Ain + (size_t)512 * 3072, 3072 * 3072 / 4);
  cvt_kernel<<<2048, 256, 0, stream>>>(Wqkv,  WqI, 9216 * 3072 / 4);
  cvt_kernel<<<2048, 256, 0, stream>>>(Wadd,  WqE, 9216 * 3072 / 4);
  cvt_kernel<<<1024, 256, 0, stream>>>(Wout,  WoI, 3072 * 3072 / 4);
  cvt_kernel<<<1024, 256, 0, stream>>>(Waddo, WoE, 3072 * 3072 / 4);

  // QKV: [3584][9216] = A_in x W^T (+ bias on enc rows), bf16 out (internal)
  gemm_bt<u16><<<dim3(72, 28), 256, 0, stream>>>(Ain, WqI, WqE, nullptr, bAdd,
                                                 qkv + (size_t)512 * 9216, qkv, 9216, 3072, 512);
  norm_rope<<<dim3(56, 24), 256, 0, stream>>>(qkv, vt, cosT, sinT, nqw, nkw, naqw, nakw);
  attn_kernel<<<dim3(28, 24), 256, 0, stream>>>(qkv, vt, aout);
  // out proj: FLOAT32 output (reference returns f32) — img rows -> d_out[0:3072*3072],
  // enc rows -> d_out[3072*3072:]
  float* outp = (float*)d_out;
  gemm_bt<float><<<dim3(24, 28), 256, 0, stream>>>(aout, WoI, WoE, bout, baddo,
                                                   outp, outp + (size_t)3072 * 3072, 3072, 3072, 512);
}

// Round 4
// 995.567 us; speedup vs baseline: 1.1336x; 1.1336x over previous
//
#include <hip/hip_runtime.h>

// Flux2 double-stream attention block, bf16 MFMA pipeline, f32 final output.
// Stages: cvt(f32->bf16) -> QKV GEMM -> RMSnorm+RoPE(+V^T) -> flash attn -> out GEMM.
// ws layout (bytes):
//   [0,           22020096)  A_in bf16 [3584][3072]   (enc rows 0..511, img 512..)   } later aliased by V^T [24][128][3584]
//   [22020096,   135266304)  Wq bf16: img [9216][3072] then enc                      } later aliased by attn_out [3584][3072]
//   [135266304,  173015040)  Wo bf16: img [3072][3072] then enc
//   [173015040,  239075328)  qkv bf16 [3584][9216] (q|k|v thirds; normed+roped in place)
// peak ws = 239,075,328 B.

typedef unsigned short u16;
typedef __attribute__((ext_vector_type(2))) unsigned short u16x2;
typedef __attribute__((ext_vector_type(4))) unsigned short u16x4;
typedef __attribute__((ext_vector_type(8))) unsigned short u16x8;
typedef __attribute__((ext_vector_type(8))) short bf16x8;
typedef __attribute__((ext_vector_type(4))) float f32x4;

#define DEV __device__ __forceinline__

DEV u16 f2bf(float f) {
  unsigned u = __builtin_bit_cast(unsigned, f);
  u = (u + 0x7FFFu + ((u >> 16) & 1u)) >> 16;   // RNE
  return (u16)u;
}
DEV float bf2f(u16 s) { return __builtin_bit_cast(float, (unsigned)s << 16); }

DEV void store_out(u16* p, float v)  { *p = f2bf(v); }
DEV void store_out(float* p, float v) { *p = v; }

#define AS1(p) (const __attribute__((address_space(1))) void*)(p)
#define AS3(p) (__attribute__((address_space(3))) void*)(p)
#define GLL16(g, l) __builtin_amdgcn_global_load_lds(AS1(g), AS3(l), 16, 0, 0)

// ---------------- fp32 -> bf16 convert ----------------
__global__ __launch_bounds__(256) void cvt_kernel(const float* __restrict__ src,
                                                  u16* __restrict__ dst, int n4) {
  int i = blockIdx.x * blockDim.x + threadIdx.x;
  int stride = gridDim.x * blockDim.x;
  for (; i < n4; i += stride) {
    float4 v = reinterpret_cast<const float4*>(src)[i];
    u16x4 o;
    o.x = f2bf(v.x); o.y = f2bf(v.y); o.z = f2bf(v.z); o.w = f2bf(v.w);
    reinterpret_cast<u16x4*>(dst)[i] = o;
  }
}

// ---------------- GEMM: C[M][N] = A[M][K] * B[N][K]^T (+bias) ----------------
// bf16 in; output type OT (bf16 for internal qkv, float for d_out).
// 128x128 tile, BK=64, 4 waves (2x2), each wave 64x64 = 4x4 frags of 16x16x32.
template <typename OT>
__global__ __launch_bounds__(256) void gemm_bt(
    const u16* __restrict__ A,
    const u16* __restrict__ Bimg, const u16* __restrict__ Benc,
    const float* __restrict__ biasImg, const float* __restrict__ biasEnc,
    OT* __restrict__ Cimg, OT* __restrict__ Cenc,
    int N, int K, int split) {
  const int nt = blockIdx.x, mt = blockIdx.y;
  const int m0 = mt * 128, n0 = nt * 128;
  const u16* B = (m0 < split) ? Benc : Bimg;
  const float* bias = (m0 < split) ? biasEnc : biasImg;
  __shared__ u16 lA[128 * 64];
  __shared__ u16 lB[128 * 64];
  const int tid = threadIdx.x, w = tid >> 6, lane = tid & 63;
  const int wm = w >> 1, wn = w & 1;
  f32x4 acc[4][4];
#pragma unroll
  for (int i = 0; i < 4; ++i)
#pragma unroll
    for (int j = 0; j < 4; ++j)
#pragma unroll
      for (int r = 0; r < 4; ++r) acc[i][j][r] = 0.f;

  for (int kb = 0; kb < K; kb += 64) {
    __syncthreads();
#pragma unroll
    for (int j = 0; j < 4; ++j) {
      int base = j * 4096 + w * 1024;          // byte offset in 16KB tile
      int off = base + lane * 16;
      int row = off >> 7;                      // 128 B per row (64 bf16)
      int colb = off & 127;
      GLL16((const char*)A + ((size_t)(m0 + row) * K + kb) * 2 + colb, (char*)lA + base);
      GLL16((const char*)B + ((size_t)(n0 + row) * K + kb) * 2 + colb, (char*)lB + base);
    }
    __syncthreads();
#pragma unroll
    for (int ks = 0; ks < 2; ++ks) {
      bf16x8 af[4], bfr[4];
#pragma unroll
      for (int i = 0; i < 4; ++i) {
        af[i]  = *(const bf16x8*)&lA[(wm * 64 + i * 16 + (lane & 15)) * 64 + ks * 32 + ((lane >> 4) << 3)];
        bfr[i] = *(const bf16x8*)&lB[(wn * 64 + i * 16 + (lane & 15)) * 64 + ks * 32 + ((lane >> 4) << 3)];
      }
#pragma unroll
      for (int i = 0; i < 4; ++i)
#pragma unroll
        for (int j = 0; j < 4; ++j)
          acc[i][j] = __builtin_amdgcn_mfma_f32_16x16x32_bf16(af[i], bfr[j], acc[i][j], 0, 0, 0);
    }
  }
  // epilogue: C[row][col], row = m*16 + (lane>>4)*4 + r, col = n*16 + (lane&15)
#pragma unroll
  for (int i = 0; i < 4; ++i) {
    int rbase = m0 + wm * 64 + i * 16 + ((lane >> 4) << 2);
#pragma unroll
    for (int j = 0; j < 4; ++j) {
      int col = n0 + wn * 64 + j * 16 + (lane & 15);
      float bv = bias ? bias[col] : 0.f;
#pragma unroll
      for (int r = 0; r < 4; ++r) {
        int row = rbase + r;
        float v = acc[i][j][r] + bv;
        if (row < split) store_out(&Cenc[(size_t)row * N + col], v);
        else             store_out(&Cimg[(size_t)(row - split) * N + col], v);
      }
    }
  }
}

// ---------------- per-head RMSnorm(q,k) + RoPE(q,k), emit V^T -----------------
// grid (56, 24): 64 seq rows x 1 head per block; wave w owns rows w*16..w*16+15.
// lane l holds d = 2l, 2l+1 (rope pair lives in one lane).
// Q is additionally pre-scaled by 1/sqrt(128) (commutes through RoPE + dot).
__global__ __launch_bounds__(256) void norm_rope(
    u16* __restrict__ qkv, u16* __restrict__ vt,
    const float* __restrict__ cosT, const float* __restrict__ sinT,
    const float* __restrict__ nqw_img, const float* __restrict__ nkw_img,
    const float* __restrict__ nqw_enc, const float* __restrict__ nkw_enc) {
  const int h = blockIdx.y;
  const int s0 = blockIdx.x * 64;
  const int tid = threadIdx.x, w = tid >> 6, lane = tid & 63;
  const bool enc = (s0 < 512);
  const float* nqw = enc ? nqw_enc : nqw_img;
  const float* nkw = enc ? nkw_enc : nkw_img;
  const float SCL = 0.088388347648318447f;  // 1/sqrt(128)
  const float wq0 = nqw[2 * lane], wq1 = nqw[2 * lane + 1];
  const float wk0 = nkw[2 * lane], wk1 = nkw[2 * lane + 1];
  u16x8 va0, va1, vb0, vb1;
#pragma unroll
  for (int r = 0; r < 16; ++r) {
    const int s = s0 + w * 16 + r;
    const size_t rowb = (size_t)s * 9216 + h * 128 + 2 * lane;
    float2 cv = *(const float2*)&cosT[(size_t)s * 128 + 2 * lane];
    float2 sv = *(const float2*)&sinT[(size_t)s * 128 + 2 * lane];
    {  // Q
      u16x2 qu = *(u16x2*)&qkv[rowb];
      float x0 = bf2f(qu.x), x1 = bf2f(qu.y);
      float ss = x0 * x0 + x1 * x1;
#pragma unroll
      for (int d = 1; d < 64; d <<= 1) ss += __shfl_xor(ss, d);
      float rms = rsqrtf(ss * (1.0f / 128.0f) + 1e-5f);
      x0 *= rms * wq0; x1 *= rms * wq1;
      float o0 = (x0 * cv.x - x1 * sv.x) * SCL;
      float o1 = (x1 * cv.y + x0 * sv.y) * SCL;
      u16x2 ou; ou.x = f2bf(o0); ou.y = f2bf(o1);
      *(u16x2*)&qkv[rowb] = ou;
    }
    {  // K
      u16x2 ku = *(u16x2*)&qkv[rowb + 3072];
      float x0 = bf2f(ku.x), x1 = bf2f(ku.y);
      float ss = x0 * x0 + x1 * x1;
#pragma unroll
      for (int d = 1; d < 64; d <<= 1) ss += __shfl_xor(ss, d);
      float rms = rsqrtf(ss * (1.0f / 128.0f) + 1e-5f);
      x0 *= rms * wk0; x1 *= rms * wk1;
      float o0 = x0 * cv.x - x1 * sv.x;
      float o1 = x1 * cv.y + x0 * sv.y;
      u16x2 ou; ou.x = f2bf(o0); ou.y = f2bf(o1);
      *(u16x2*)&qkv[rowb + 3072] = ou;
    }
    {  // V -> registers for transposed store
      u16x2 vu = *(u16x2*)&qkv[rowb + 6144];
      if (r < 8) { va0[r] = vu.x; vb0[r] = vu.y; }
      else       { va1[r - 8] = vu.x; vb1[r - 8] = vu.y; }
    }
  }
  // V^T[h][d][s]: lane writes its two d-rows, 16 contiguous s each (2x16B stores/row)
  const size_t vbase = (size_t)h * 128 * 3584 + (size_t)(2 * lane) * 3584 + s0 + w * 16;
  *(u16x8*)&vt[vbase]            = va0;
  *(u16x8*)&vt[vbase + 8]        = va1;
  *(u16x8*)&vt[vbase + 3584]     = vb0;
  *(u16x8*)&vt[vbase + 3584 + 8] = vb1;
}

// ---------------- flash attention ----------------
// grid (56, 24): q-tile of 64 rows x head. 4 waves, each 16 q-rows (QBLK=16/wave
// to cut VGPR below 128 -> 4 waves/SIMD; LDS 40KB -> 4 blocks/CU).
// K tile [64][128] and V^T tile [128][64] staged to LDS with XOR-swizzled
// global source + linear global_load_lds dest (rule #21); reads apply same XOR.
// Q pre-scaled by 1/sqrt(128) in norm_rope. Defer-max (T13, THR=8).
__global__ __launch_bounds__(256, 4) void attn_kernel(
    const u16* __restrict__ qkv, const u16* __restrict__ vt,
    u16* __restrict__ aout) {
  const int h = blockIdx.y, qt = blockIdx.x;
  const int tid = threadIdx.x, w = tid >> 6, lane = tid & 63;
  const int qbase = qt * 64 + w * 16;
  __shared__ u16 Klds[64 * 128];
  __shared__ u16 Vlds[128 * 64];
  __shared__ u16 Plds[4][1024];  // per-wave 16x64 bf16 (row stride 128B, XOR swz)

  bf16x8 aq[4];
  {
    const u16* qp = qkv + (size_t)(qbase + (lane & 15)) * 9216 + h * 128 + ((lane >> 4) << 3);
#pragma unroll
    for (int ks = 0; ks < 4; ++ks) aq[ks] = *(const bf16x8*)(qp + ks * 32);
  }
  float m_i[4], l_i[4];
  f32x4 o[8];
#pragma unroll
  for (int r = 0; r < 4; ++r) { m_i[r] = -1e30f; l_i[r] = 0.f; }
#pragma unroll
  for (int dt = 0; dt < 8; ++dt)
#pragma unroll
    for (int r = 0; r < 4; ++r) o[dt][r] = 0.f;
  const size_t vhead = (size_t)h * 128 * 3584;

  for (int kt0 = 0; kt0 < 3584; kt0 += 64) {
    __syncthreads();
#pragma unroll
    for (int j = 0; j < 4; ++j) {  // K tile: 64 rows x 256B
      int base = w * 4096 + j * 1024;
      int off = base + lane * 16;
      int row = off >> 8;
      int src = (off & 255) ^ ((row & 7) << 4);
      GLL16((const char*)(qkv + (size_t)(kt0 + row) * 9216 + 3072 + h * 128) + src, (char*)Klds + base);
    }
#pragma unroll
    for (int j = 0; j < 4; ++j) {  // V^T tile: 128 rows x 128B
      int base = w * 4096 + j * 1024;
      int off = base + lane * 16;
      int d = off >> 7;
      int src = (off & 127) ^ ((d & 7) << 4);
      GLL16((const char*)(vt + vhead + (size_t)d * 3584 + kt0) + src, (char*)Vlds + base);
    }
    __syncthreads();

    // S = Q K^T  (already includes 1/sqrt(128) via pre-scaled Q)
    f32x4 sacc[4];
#pragma unroll
    for (int kt = 0; kt < 4; ++kt)
#pragma unroll
      for (int r = 0; r < 4; ++r) sacc[kt][r] = 0.f;
#pragma unroll
    for (int kt = 0; kt < 4; ++kt) {
      const int row = kt * 16 + (lane & 15);
      bf16x8 bk[4];
#pragma unroll
      for (int ks = 0; ks < 4; ++ks) {
        int cb = (ks * 32 + ((lane >> 4) << 3)) * 2;
        bk[ks] = *(const bf16x8*)((const char*)Klds + (row * 256 + (cb ^ ((row & 7) << 4))));
      }
#pragma unroll
      for (int ks = 0; ks < 4; ++ks)
        sacc[kt] = __builtin_amdgcn_mfma_f32_16x16x32_bf16(aq[ks], bk[ks], sacc[kt], 0, 0, 0);
    }

    // online softmax with defer-max (skip rescale while tile max - m <= 8)
    float mx[4];
#pragma unroll
    for (int r = 0; r < 4; ++r) {
      float m = fmaxf(fmaxf(sacc[0][r], sacc[1][r]), fmaxf(sacc[2][r], sacc[3][r]));
#pragma unroll
      for (int d = 1; d < 16; d <<= 1) m = fmaxf(m, __shfl_xor(m, d));
      mx[r] = m;
    }
    bool ok = (mx[0] - m_i[0] <= 8.f) && (mx[1] - m_i[1] <= 8.f) &&
              (mx[2] - m_i[2] <= 8.f) && (mx[3] - m_i[3] <= 8.f);
    if (!__all(ok)) {
#pragma unroll
      for (int r = 0; r < 4; ++r) {
        float mnew = fmaxf(m_i[r], mx[r]);
        float alpha = __expf(m_i[r] - mnew);
        m_i[r] = mnew;
        l_i[r] *= alpha;
#pragma unroll
        for (int dt = 0; dt < 8; ++dt) o[dt][r] *= alpha;
      }
    }
    float psum[4] = {0.f, 0.f, 0.f, 0.f};
#pragma unroll
    for (int kt = 0; kt < 4; ++kt) {
      const int col = kt * 16 + (lane & 15);
#pragma unroll
      for (int r = 0; r < 4; ++r) {
        float p = __expf(sacc[kt][r] - m_i[r]);   // bounded by e^8
        psum[r] += p;
        const int prow = ((lane >> 4) << 2) + r;
        // truncating bf16 (1 op; bias ~2^-9 relative, negligible vs threshold)
        *(u16*)((char*)Plds[w] + ((prow * 128 + col * 2) ^ ((prow & 7) << 4))) =
            (u16)(__builtin_bit_cast(unsigned, p) >> 16);
      }
    }
#pragma unroll
    for (int r = 0; r < 4; ++r) {
      float ps = psum[r];
#pragma unroll
      for (int d = 1; d < 16; d <<= 1) ps += __shfl_xor(ps, d);
      l_i[r] += ps;
    }

    // O += P V   (P from per-wave LDS as A-frag; V^T rows are the B-operand)
    bf16x8 pa[2];
    {
      const int prow = lane & 15;
#pragma unroll
      for (int ks = 0; ks < 2; ++ks) {
        int cb = (ks * 32 + ((lane >> 4) << 3)) * 2;
        pa[ks] = *(const bf16x8*)((const char*)Plds[w] + ((prow * 128 + cb) ^ ((prow & 7) << 4)));
      }
    }
#pragma unroll
    for (int dt = 0; dt < 8; ++dt) {
      const int vrow = dt * 16 + (lane & 15);
      bf16x8 bv[2];
#pragma unroll
      for (int ks = 0; ks < 2; ++ks) {
        int cb = (ks * 32 + ((lane >> 4) << 3)) * 2;
        bv[ks] = *(const bf16x8*)((const char*)Vlds + ((vrow * 128 + cb) ^ ((vrow & 7) << 4)));
      }
      o[dt] = __builtin_amdgcn_mfma_f32_16x16x32_bf16(pa[0], bv[0], o[dt], 0, 0, 0);
      o[dt] = __builtin_amdgcn_mfma_f32_16x16x32_bf16(pa[1], bv[1], o[dt], 0, 0, 0);
    }
  }

  // epilogue: O /= l, scatter bf16 to attn_out[s][h*128+d]
#pragma unroll
  for (int r = 0; r < 4; ++r) {
    const float inv = 1.0f / l_i[r];
    const int s = qbase + ((lane >> 4) << 2) + r;
#pragma unroll
    for (int dt = 0; dt < 8; ++dt) {
      aout[(size_t)s * 3072 + h * 128 + dt * 16 + (lane & 15)] = f2bf(o[dt][r] * inv);
    }
  }
}

extern "C" void kernel_launch(void* const* d_in, const int* in_sizes, int n_in,
                              void* d_out, int out_size, void* d_ws, size_t ws_size,
                              hipStream_t stream) {
  (void)in_sizes; (void)n_in; (void)out_size; (void)ws_size;
  const float* hs    = (const float*)d_in[0];
  const float* ehs   = (const float*)d_in[1];
  const float* cosT  = (const float*)d_in[2];
  const float* sinT  = (const float*)d_in[3];
  const float* Wqkv  = (const float*)d_in[4];
  const float* Wadd  = (const float*)d_in[5];
  const float* bAdd  = (const float*)d_in[6];
  const float* nqw   = (const float*)d_in[7];
  const float* nkw   = (const float*)d_in[8];
  const float* naqw  = (const float*)d_in[9];
  const float* nakw  = (const float*)d_in[10];
  const float* Wout  = (const float*)d_in[11];
  const float* bout  = (const float*)d_in[12];
  const float* Waddo = (const float*)d_in[13];
  const float* baddo = (const float*)d_in[14];

  char* ws = (char*)d_ws;
  u16* Ain = (u16*)(ws);                       // [3584][3072]
  u16* WqI = (u16*)(ws + 22020096);            // [9216][3072]
  u16* WqE = WqI + (size_t)9216 * 3072;
  u16* WoI = (u16*)(ws + 135266304);           // [3072][3072]
  u16* WoE = WoI + (size_t)3072 * 3072;
  u16* qkv = (u16*)(ws + 173015040);           // [3584][9216]
  u16* vt   = Ain;  // alias: A_in dead after QKV GEMM
  u16* aout = WqI;  // alias: W_qkv dead after QKV GEMM

  cvt_kernel<<<1024, 256, 0, stream>>>(ehs,   Ain,                      512 * 3072 / 4);
  cvt_kernel<<<1024, 256, 0, stream>>>(hs,    Ain + (size_t)512 * 3072, 3072 * 3072 / 4);
  cvt_kernel<<<2048, 256, 0, stream>>>(Wqkv,  WqI, 9216 * 3072 / 4);
  cvt_kernel<<<2048, 256, 0, stream>>>(Wadd,  WqE, 9216 * 3072 / 4);
  cvt_kernel<<<1024, 256, 0, stream>>>(Wout,  WoI, 3072 * 3072 / 4);
  cvt_kernel<<<1024, 256, 0, stream>>>(Waddo, WoE, 3072 * 3072 / 4);

  // QKV: [3584][9216] = A_in x W^T (+ bias on enc rows), bf16 out (internal)
  gemm_bt<u16><<<dim3(72, 28), 256, 0, stream>>>(Ain, WqI, WqE, nullptr, bAdd,
                                                 qkv + (size_t)512 * 9216, qkv, 9216, 3072, 512);
  norm_rope<<<dim3(56, 24), 256, 0, stream>>>(qkv, vt, cosT, sinT, nqw, nkw, naqw, nakw);
  attn_kernel<<<dim3(56, 24), 256, 0, stream>>>(qkv, vt, aout);
  // out proj: FLOAT32 output — img rows -> d_out[0:3072*3072], enc rows after
  float* outp = (float*)d_out;
  gemm_bt<float><<<dim3(24, 28), 256, 0, stream>>>(aout, WoI, WoE, bout, baddo,
                                                   outp, outp + (size_t)3072 * 3072, 3072, 3072, 512);
}

// Round 5
// 887.788 us; speedup vs baseline: 1.2713x; 1.1214x over previous
//
#include <hip/hip_runtime.h>

// Flux2 double-stream attention block, bf16 MFMA pipeline, f32 final output.
// Stages: cvt(f32->bf16) -> QKV GEMM -> RMSnorm+RoPE(+V^T) -> flash attn -> out GEMM.
// ws layout (bytes):
//   [0,           22020096)  A_in bf16 [3584][3072]   (enc rows 0..511, img 512..)   } later aliased by V^T [24][128][3584]
//   [22020096,   135266304)  Wq bf16: img [9216][3072] then enc                      } later aliased by attn_out [3584][3072]
//   [135266304,  173015040)  Wo bf16: img [3072][3072] then enc
//   [173015040,  239075328)  qkv bf16 [3584][9216] (q|k|v thirds; normed+roped in place)
// peak ws = 239,075,328 B.

typedef unsigned short u16;
typedef __attribute__((ext_vector_type(2))) unsigned short u16x2;
typedef __attribute__((ext_vector_type(4))) unsigned short u16x4;
typedef __attribute__((ext_vector_type(8))) unsigned short u16x8;
typedef __attribute__((ext_vector_type(8))) short bf16x8;
typedef __attribute__((ext_vector_type(4))) float f32x4;

#define DEV __device__ __forceinline__

DEV u16 f2bf(float f) {
  unsigned u = __builtin_bit_cast(unsigned, f);
  u = (u + 0x7FFFu + ((u >> 16) & 1u)) >> 16;   // RNE
  return (u16)u;
}
DEV float bf2f(u16 s) { return __builtin_bit_cast(float, (unsigned)s << 16); }

DEV void store_out(u16* p, float v)  { *p = f2bf(v); }
DEV void store_out(float* p, float v) { *p = v; }

#define AS1(p) (const __attribute__((address_space(1))) void*)(p)
#define AS3(p) (__attribute__((address_space(3))) void*)(p)
#define GLL16(g, l) __builtin_amdgcn_global_load_lds(AS1(g), AS3(l), 16, 0, 0)

// ---------------- fp32 -> bf16 convert ----------------
__global__ __launch_bounds__(256) void cvt_kernel(const float* __restrict__ src,
                                                  u16* __restrict__ dst, int n4) {
  int i = blockIdx.x * blockDim.x + threadIdx.x;
  int stride = gridDim.x * blockDim.x;
  for (; i < n4; i += stride) {
    float4 v = reinterpret_cast<const float4*>(src)[i];
    u16x4 o;
    o.x = f2bf(v.x); o.y = f2bf(v.y); o.z = f2bf(v.z); o.w = f2bf(v.w);
    reinterpret_cast<u16x4*>(dst)[i] = o;
  }
}

// ---------------- GEMM: C[M][N] = A[M][K] * B[N][K]^T (+bias) ----------------
// bf16 in; output type OT (bf16 for internal qkv, float for d_out).
// 128x128 tile, BK=64, 4 waves (2x2), each wave 64x64 = 4x4 frags of 16x16x32.
template <typename OT>
__global__ __launch_bounds__(256) void gemm_bt(
    const u16* __restrict__ A,
    const u16* __restrict__ Bimg, const u16* __restrict__ Benc,
    const float* __restrict__ biasImg, const float* __restrict__ biasEnc,
    OT* __restrict__ Cimg, OT* __restrict__ Cenc,
    int N, int K, int split) {
  const int nt = blockIdx.x, mt = blockIdx.y;
  const int m0 = mt * 128, n0 = nt * 128;
  const u16* B = (m0 < split) ? Benc : Bimg;
  const float* bias = (m0 < split) ? biasEnc : biasImg;
  __shared__ u16 lA[128 * 64];
  __shared__ u16 lB[128 * 64];
  const int tid = threadIdx.x, w = tid >> 6, lane = tid & 63;
  const int wm = w >> 1, wn = w & 1;
  f32x4 acc[4][4];
#pragma unroll
  for (int i = 0; i < 4; ++i)
#pragma unroll
    for (int j = 0; j < 4; ++j)
#pragma unroll
      for (int r = 0; r < 4; ++r) acc[i][j][r] = 0.f;

  for (int kb = 0; kb < K; kb += 64) {
    __syncthreads();
#pragma unroll
    for (int j = 0; j < 4; ++j) {
      int base = j * 4096 + w * 1024;          // byte offset in 16KB tile
      int off = base + lane * 16;
      int row = off >> 7;                      // 128 B per row (64 bf16)
      int colb = off & 127;
      GLL16((const char*)A + ((size_t)(m0 + row) * K + kb) * 2 + colb, (char*)lA + base);
      GLL16((const char*)B + ((size_t)(n0 + row) * K + kb) * 2 + colb, (char*)lB + base);
    }
    __syncthreads();
#pragma unroll
    for (int ks = 0; ks < 2; ++ks) {
      bf16x8 af[4], bfr[4];
#pragma unroll
      for (int i = 0; i < 4; ++i) {
        af[i]  = *(const bf16x8*)&lA[(wm * 64 + i * 16 + (lane & 15)) * 64 + ks * 32 + ((lane >> 4) << 3)];
        bfr[i] = *(const bf16x8*)&lB[(wn * 64 + i * 16 + (lane & 15)) * 64 + ks * 32 + ((lane >> 4) << 3)];
      }
#pragma unroll
      for (int i = 0; i < 4; ++i)
#pragma unroll
        for (int j = 0; j < 4; ++j)
          acc[i][j] = __builtin_amdgcn_mfma_f32_16x16x32_bf16(af[i], bfr[j], acc[i][j], 0, 0, 0);
    }
  }
  // epilogue: C[row][col], row = m*16 + (lane>>4)*4 + r, col = n*16 + (lane&15)
#pragma unroll
  for (int i = 0; i < 4; ++i) {
    int rbase = m0 + wm * 64 + i * 16 + ((lane >> 4) << 2);
#pragma unroll
    for (int j = 0; j < 4; ++j) {
      int col = n0 + wn * 64 + j * 16 + (lane & 15);
      float bv = bias ? bias[col] : 0.f;
#pragma unroll
      for (int r = 0; r < 4; ++r) {
        int row = rbase + r;
        float v = acc[i][j][r] + bv;
        if (row < split) store_out(&Cenc[(size_t)row * N + col], v);
        else             store_out(&Cimg[(size_t)(row - split) * N + col], v);
      }
    }
  }
}

// ---------------- per-head RMSnorm(q,k) + RoPE(q,k), emit V^T -----------------
// grid (56, 24): 64 seq rows x 1 head per block; wave w owns rows w*16..w*16+15.
// lane l holds d = 2l, 2l+1 (rope pair lives in one lane).
// Q is pre-scaled by log2(e)/sqrt(128): QK^T then lands in log2 units so the
// attn kernel can use v_exp_f32 (2^x) directly with no per-element multiply.
__global__ __launch_bounds__(256) void norm_rope(
    u16* __restrict__ qkv, u16* __restrict__ vt,
    const float* __restrict__ cosT, const float* __restrict__ sinT,
    const float* __restrict__ nqw_img, const float* __restrict__ nkw_img,
    const float* __restrict__ nqw_enc, const float* __restrict__ nkw_enc) {
  const int h = blockIdx.y;
  const int s0 = blockIdx.x * 64;
  const int tid = threadIdx.x, w = tid >> 6, lane = tid & 63;
  const bool enc = (s0 < 512);
  const float* nqw = enc ? nqw_enc : nqw_img;
  const float* nkw = enc ? nkw_enc : nkw_img;
  const float SCL = 0.12751743f;  // log2(e)/sqrt(128)
  const float wq0 = nqw[2 * lane], wq1 = nqw[2 * lane + 1];
  const float wk0 = nkw[2 * lane], wk1 = nkw[2 * lane + 1];
  u16x8 va0, va1, vb0, vb1;
#pragma unroll
  for (int r = 0; r < 16; ++r) {
    const int s = s0 + w * 16 + r;
    const size_t rowb = (size_t)s * 9216 + h * 128 + 2 * lane;
    float2 cv = *(const float2*)&cosT[(size_t)s * 128 + 2 * lane];
    float2 sv = *(const float2*)&sinT[(size_t)s * 128 + 2 * lane];
    {  // Q
      u16x2 qu = *(u16x2*)&qkv[rowb];
      float x0 = bf2f(qu.x), x1 = bf2f(qu.y);
      float ss = x0 * x0 + x1 * x1;
#pragma unroll
      for (int d = 1; d < 64; d <<= 1) ss += __shfl_xor(ss, d);
      float rms = rsqrtf(ss * (1.0f / 128.0f) + 1e-5f);
      x0 *= rms * wq0; x1 *= rms * wq1;
      float o0 = (x0 * cv.x - x1 * sv.x) * SCL;
      float o1 = (x1 * cv.y + x0 * sv.y) * SCL;
      u16x2 ou; ou.x = f2bf(o0); ou.y = f2bf(o1);
      *(u16x2*)&qkv[rowb] = ou;
    }
    {  // K
      u16x2 ku = *(u16x2*)&qkv[rowb + 3072];
      float x0 = bf2f(ku.x), x1 = bf2f(ku.y);
      float ss = x0 * x0 + x1 * x1;
#pragma unroll
      for (int d = 1; d < 64; d <<= 1) ss += __shfl_xor(ss, d);
      float rms = rsqrtf(ss * (1.0f / 128.0f) + 1e-5f);
      x0 *= rms * wk0; x1 *= rms * wk1;
      float o0 = x0 * cv.x - x1 * sv.x;
      float o1 = x1 * cv.y + x0 * sv.y;
      u16x2 ou; ou.x = f2bf(o0); ou.y = f2bf(o1);
      *(u16x2*)&qkv[rowb + 3072] = ou;
    }
    {  // V -> registers for transposed store
      u16x2 vu = *(u16x2*)&qkv[rowb + 6144];
      if (r < 8) { va0[r] = vu.x; vb0[r] = vu.y; }
      else       { va1[r - 8] = vu.x; vb1[r - 8] = vu.y; }
    }
  }
  // V^T[h][d][s]: lane writes its two d-rows, 16 contiguous s each (2x16B stores/row)
  const size_t vbase = (size_t)h * 128 * 3584 + (size_t)(2 * lane) * 3584 + s0 + w * 16;
  *(u16x8*)&vt[vbase]            = va0;
  *(u16x8*)&vt[vbase + 8]        = va1;
  *(u16x8*)&vt[vbase + 3584]     = vb0;
  *(u16x8*)&vt[vbase + 3584 + 8] = vb1;
}

// ---------------- flash attention ----------------
// 1-D grid of 1344 blocks; decode (qt, h) so each XCD (lid%8 round-robin) gets
// only 3 heads -> K/V working set per XCD-L2 = 5.4 MB instead of 44 MB.
// 4 waves, each 16 q-rows. K tile [64][128] and V^T tile [128][64] staged via
// XOR-swizzled-source global_load_lds (rule #21); reads apply same XOR.
// SWAPPED QK^T: sacc = mfma(K_frag, Q_frag) -> lane holds S^T[k][q] with
// q = lane&15 fixed, k = kt*16 + (lane>>4)*4 + r. Softmax reduce = 15 local
// fmax + 2 shfl (was 16 shfl); m/l are scalars; P stored as 4x ds_write_b64
// (was 16 scalar u16 writes). Scores in log2 units (Q pre-scaled) -> v_exp_f32.
__global__ __launch_bounds__(256, 4) void attn_kernel(
    const u16* __restrict__ qkv, const u16* __restrict__ vt,
    u16* __restrict__ aout) {
  const int bid = blockIdx.x;
  const int qt = bid / 24;
  const int rr = bid % 24;
  const int h = (rr % 8) * 3 + (rr / 8);   // bijective; clusters heads per XCD
  const int tid = threadIdx.x, w = tid >> 6, lane = tid & 63;
  const int qbase = qt * 64 + w * 16;
  const int q = lane & 15, hi = lane >> 4;
  __shared__ u16 Klds[64 * 128];
  __shared__ u16 Vlds[128 * 64];
  __shared__ u16 Plds[4][1024];  // per-wave P[16 q][64 k] bf16, XOR-swizzled rows

  bf16x8 aq[4];  // Q rows as B-operand (cols=q): same addressing as before
  {
    const u16* qp = qkv + (size_t)(qbase + q) * 9216 + h * 128 + (hi << 3);
#pragma unroll
    for (int ks = 0; ks < 4; ++ks) aq[ks] = *(const bf16x8*)(qp + ks * 32);
  }
  float m_i = -1e30f, l_i = 0.f;  // state for q-row (qbase + q), log2 domain
  f32x4 o[8];                     // O[q'=hi*4+r][d=dt*16+q]
#pragma unroll
  for (int dt = 0; dt < 8; ++dt)
#pragma unroll
    for (int r = 0; r < 4; ++r) o[dt][r] = 0.f;
  const size_t vhead = (size_t)h * 128 * 3584;

  for (int kt0 = 0; kt0 < 3584; kt0 += 64) {
    __syncthreads();
#pragma unroll
    for (int j = 0; j < 4; ++j) {  // K tile: 64 rows x 256B
      int base = w * 4096 + j * 1024;
      int off = base + lane * 16;
      int row = off >> 8;
      int src = (off & 255) ^ ((row & 7) << 4);
      GLL16((const char*)(qkv + (size_t)(kt0 + row) * 9216 + 3072 + h * 128) + src, (char*)Klds + base);
    }
#pragma unroll
    for (int j = 0; j < 4; ++j) {  // V^T tile: 128 rows x 128B
      int base = w * 4096 + j * 1024;
      int off = base + lane * 16;
      int d = off >> 7;
      int src = (off & 127) ^ ((d & 7) << 4);
      GLL16((const char*)(vt + vhead + (size_t)d * 3584 + kt0) + src, (char*)Vlds + base);
    }
    __syncthreads();

    // S^T = K Q^T (swapped operands; log2 units via pre-scaled Q)
    f32x4 sacc[4];
#pragma unroll
    for (int kt = 0; kt < 4; ++kt)
#pragma unroll
      for (int r = 0; r < 4; ++r) sacc[kt][r] = 0.f;
    __builtin_amdgcn_s_setprio(1);
#pragma unroll
    for (int kt = 0; kt < 4; ++kt) {
      const int row = kt * 16 + q;
      bf16x8 bk[4];
#pragma unroll
      for (int ks = 0; ks < 4; ++ks) {
        int cb = (ks * 32 + (hi << 3)) * 2;
        bk[ks] = *(const bf16x8*)((const char*)Klds + (row * 256 + (cb ^ ((row & 7) << 4))));
      }
#pragma unroll
      for (int ks = 0; ks < 4; ++ks)
        sacc[kt] = __builtin_amdgcn_mfma_f32_16x16x32_bf16(bk[ks], aq[ks], sacc[kt], 0, 0, 0);
    }
    __builtin_amdgcn_s_setprio(0);

    // online softmax, defer-max (THR=8 in log2 units -> P bounded by 256)
    float mx = sacc[0][0];
#pragma unroll
    for (int kt = 0; kt < 4; ++kt)
#pragma unroll
      for (int r = 0; r < 4; ++r) mx = fmaxf(mx, sacc[kt][r]);
    mx = fmaxf(mx, __shfl_xor(mx, 16));
    mx = fmaxf(mx, __shfl_xor(mx, 32));
    if (!__all(mx - m_i <= 8.f)) {
      float mnew = fmaxf(m_i, mx);
      float alpha = __builtin_amdgcn_exp2f(m_i - mnew);
      m_i = mnew;
      l_i *= alpha;
      // o rows are q'=hi*4+r; fetch alpha from the lane holding that q
#pragma unroll
      for (int r = 0; r < 4; ++r) {
        float ar = __shfl(alpha, (lane & 48) | ((hi << 2) + r));
#pragma unroll
        for (int dt = 0; dt < 8; ++dt) o[dt][r] *= ar;
      }
    }
    float psum = 0.f;
#pragma unroll
    for (int kt = 0; kt < 4; ++kt) {
      u16x4 pw;
#pragma unroll
      for (int r = 0; r < 4; ++r) {
        float p = __builtin_amdgcn_exp2f(sacc[kt][r] - m_i);
        psum += p;
        pw[r] = (u16)(__builtin_bit_cast(unsigned, p) >> 16);  // trunc bf16
      }
      // P[q][k], k = kt*16 + hi*4 + r: one 8B write of 4 consecutive k
      *(u16x4*)((char*)Plds[w] + ((q * 128 + kt * 32 + hi * 8) ^ ((q & 7) << 4))) = pw;
    }
    psum += __shfl_xor(psum, 16);
    psum += __shfl_xor(psum, 32);
    l_i += psum;

    // O += P V   (P from per-wave LDS as A-frag; V^T rows are the B-operand)
    bf16x8 pa[2];
#pragma unroll
    for (int ks = 0; ks < 2; ++ks) {
      int cb = (ks * 32 + (hi << 3)) * 2;
      pa[ks] = *(const bf16x8*)((const char*)Plds[w] + ((q * 128 + cb) ^ ((q & 7) << 4)));
    }
    __builtin_amdgcn_s_setprio(1);
#pragma unroll
    for (int dt = 0; dt < 8; ++dt) {
      const int vrow = dt * 16 + q;
      bf16x8 bv[2];
#pragma unroll
      for (int ks = 0; ks < 2; ++ks) {
        int cb = (ks * 32 + (hi << 3)) * 2;
        bv[ks] = *(const bf16x8*)((const char*)Vlds + ((vrow * 128 + cb) ^ ((vrow & 7) << 4)));
      }
      o[dt] = __builtin_amdgcn_mfma_f32_16x16x32_bf16(pa[0], bv[0], o[dt], 0, 0, 0);
      o[dt] = __builtin_amdgcn_mfma_f32_16x16x32_bf16(pa[1], bv[1], o[dt], 0, 0, 0);
    }
    __builtin_amdgcn_s_setprio(0);
  }

  // epilogue: O /= l (l fetched from the lane owning that q-row), bf16 scatter
#pragma unroll
  for (int r = 0; r < 4; ++r) {
    const int q2 = (hi << 2) + r;
    const float lr = __shfl(l_i, (lane & 48) | q2);
    const float inv = 1.0f / lr;
    const int s = qbase + q2;
#pragma unroll
    for (int dt = 0; dt < 8; ++dt) {
      aout[(size_t)s * 3072 + h * 128 + dt * 16 + q] = f2bf(o[dt][r] * inv);
    }
  }
}

extern "C" void kernel_launch(void* const* d_in, const int* in_sizes, int n_in,
                              void* d_out, int out_size, void* d_ws, size_t ws_size,
                              hipStream_t stream) {
  (void)in_sizes; (void)n_in; (void)out_size; (void)ws_size;
  const float* hs    = (const float*)d_in[0];
  const float* ehs   = (const float*)d_in[1];
  const float* cosT  = (const float*)d_in[2];
  const float* sinT  = (const float*)d_in[3];
  const float* Wqkv  = (const float*)d_in[4];
  const float* Wadd  = (const float*)d_in[5];
  const float* bAdd  = (const float*)d_in[6];
  const float* nqw   = (const float*)d_in[7];
  const float* nkw   = (const float*)d_in[8];
  const float* naqw  = (const float*)d_in[9];
  const float* nakw  = (const float*)d_in[10];
  const float* Wout  = (const float*)d_in[11];
  const float* bout  = (const float*)d_in[12];
  const float* Waddo = (const float*)d_in[13];
  const float* baddo = (const float*)d_in[14];

  char* ws = (char*)d_ws;
  u16* Ain = (u16*)(ws);                       // [3584][3072]
  u16* WqI = (u16*)(ws + 22020096);            // [9216][3072]
  u16* WqE = WqI + (size_t)9216 * 3072;
  u16* WoI = (u16*)(ws + 135266304);           // [3072][3072]
  u16* WoE = WoI + (size_t)3072 * 3072;
  u16* qkv = (u16*)(ws + 173015040);           // [3584][9216]
  u16* vt   = Ain;  // alias: A_in dead after QKV GEMM
  u16* aout = WqI;  // alias: W_qkv dead after QKV GEMM

  cvt_kernel<<<1024, 256, 0, stream>>>(ehs,   Ain,                      512 * 3072 / 4);
  cvt_kernel<<<1024, 256, 0, stream>>>(hs,    Ain + (size_t)512 * 3072, 3072 * 3072 / 4);
  cvt_kernel<<<2048, 256, 0, stream>>>(Wqkv,  WqI, 9216 * 3072 / 4);
  cvt_kernel<<<2048, 256, 0, stream>>>(Wadd,  WqE, 9216 * 3072 / 4);
  cvt_kernel<<<1024, 256, 0, stream>>>(Wout,  WoI, 3072 * 3072 / 4);
  cvt_kernel<<<1024, 256, 0, stream>>>(Waddo, WoE, 3072 * 3072 / 4);

  // QKV: [3584][9216] = A_in x W^T (+ bias on enc rows), bf16 out (internal)
  gemm_bt<u16><<<dim3(72, 28), 256, 0, stream>>>(Ain, WqI, WqE, nullptr, bAdd,
                                                 qkv + (size_t)512 * 9216, qkv, 9216, 3072, 512);
  norm_rope<<<dim3(56, 24), 256, 0, stream>>>(qkv, vt, cosT, sinT, nqw, nkw, naqw, nakw);
  attn_kernel<<<dim3(1344), 256, 0, stream>>>(qkv, vt, aout);
  // out proj: FLOAT32 output — img rows -> d_out[0:3072*3072], enc rows after
  float* outp = (float*)d_out;
  gemm_bt<float><<<dim3(24, 28), 256, 0, stream>>>(aout, WoI, WoE, bout, baddo,
                                                   outp, outp + (size_t)3072 * 3072, 3072, 3072, 512);
}

// Round 6
// 738.401 us; speedup vs baseline: 1.5285x; 1.2023x over previous
//
#include <hip/hip_runtime.h>

// Flux2 double-stream attention block, bf16 MFMA pipeline, f32 final output.
// Stages: cvt(f32->bf16) -> QKV GEMM (8-phase 256^2) -> RMSnorm+RoPE(+V^T)
//         -> flash attn -> out GEMM (8-phase 256^2).
// ws layout (bytes):
//   [0,           22020096)  A_in bf16 [3584][3072]   } later aliased by V^T [24][128][3584]
//   [22020096,   135266304)  Wq bf16: img [9216][3072] then enc } later aliased by attn_out
//   [135266304,  173015040)  Wo bf16: img [3072][3072] then enc
//   [173015040,  239075328)  qkv bf16 [3584][9216]
// peak ws = 239,075,328 B.

typedef unsigned short u16;
typedef __attribute__((ext_vector_type(2))) unsigned short u16x2;
typedef __attribute__((ext_vector_type(4))) unsigned short u16x4;
typedef __attribute__((ext_vector_type(8))) unsigned short u16x8;
typedef __attribute__((ext_vector_type(8))) short bf16x8;
typedef __attribute__((ext_vector_type(4))) float f32x4;

#define DEV __device__ __forceinline__

DEV u16 f2bf(float f) {
  unsigned u = __builtin_bit_cast(unsigned, f);
  u = (u + 0x7FFFu + ((u >> 16) & 1u)) >> 16;   // RNE
  return (u16)u;
}
DEV float bf2f(u16 s) { return __builtin_bit_cast(float, (unsigned)s << 16); }

DEV void store_out(u16* p, float v)  { *p = f2bf(v); }
DEV void store_out(float* p, float v) { *p = v; }

#define AS1(p) (const __attribute__((address_space(1))) void*)(p)
#define AS3(p) (__attribute__((address_space(3))) void*)(p)
#define GLL16(g, l) __builtin_amdgcn_global_load_lds(AS1(g), AS3(l), 16, 0, 0)

// raw barrier (NOT __syncthreads: that emits s_waitcnt vmcnt(0) and drains the
// counted-vmcnt pipeline). Compiler-only memory fences pin op order around it.
#define BAR() do { asm volatile("" ::: "memory"); __builtin_amdgcn_s_barrier(); \
                   asm volatile("" ::: "memory"); } while (0)
#define VMC8() asm volatile("s_waitcnt vmcnt(8)" ::: "memory")
#define VMC0() asm volatile("s_waitcnt vmcnt(0)" ::: "memory")

// ---------------- fp32 -> bf16 convert ----------------
__global__ __launch_bounds__(256) void cvt_kernel(const float* __restrict__ src,
                                                  u16* __restrict__ dst, int n4) {
  int i = blockIdx.x * blockDim.x + threadIdx.x;
  int stride = gridDim.x * blockDim.x;
  for (; i < n4; i += stride) {
    float4 v = reinterpret_cast<const float4*>(src)[i];
    u16x4 o;
    o.x = f2bf(v.x); o.y = f2bf(v.y); o.z = f2bf(v.z); o.w = f2bf(v.w);
    reinterpret_cast<u16x4*>(dst)[i] = o;
  }
}

// ---------------- GEMM (8-phase 256x256): C = A[M][K] * B[N][K]^T (+bias) ----
// 512 threads = 8 waves (2M x 4N), wave tile 128x64, BK=64, 2 K-tiles/iter in
// a 128 KiB LDS double buffer. Per half: 4 phases x {ds_read quad -> setprio ->
// 16 MFMA}, phase-end raw barriers. Stages (8 x global_load_lds w=16, XOR-
// swizzled SOURCE + linear dest, rule #21) issued only after the target
// buffer's reads completed; vmcnt(8) counted (T4), never 0 in steady state.
// Reads apply the same XOR involution: cb ^= ((row&7)<<4)  -> 2-way max.
template <typename OT>
__global__ __launch_bounds__(512, 2) void gemm256(
    const u16* __restrict__ A,
    const u16* __restrict__ Bimg, const u16* __restrict__ Benc,
    const float* __restrict__ biasImg, const float* __restrict__ biasEnc,
    OT* __restrict__ Cimg, OT* __restrict__ Cenc,
    int N, int K, int split, int nwg) {
  // bijective XCD swizzle (nwg % 8 == 0): XCD x owns a contiguous tile chunk
  const int bid = blockIdx.x;
  const int swz = (bid & 7) * (nwg >> 3) + (bid >> 3);
  const int ntn = N >> 8;
  const int mt = swz / ntn, nt = swz % ntn;
  const int m0 = mt << 8, n0 = nt << 8;
  const u16* B = (m0 < split) ? Benc : Bimg;
  const float* bias = (m0 < split) ? biasEnc : biasImg;

  __shared__ u16 lds[2][2][16384];  // [buf][A=0/B=1][256 rows x 64 bf16] x2 = 128 KiB

  const int tid = threadIdx.x, w = tid >> 6, lane = tid & 63;
  const int wm = w >> 2, wn = w & 3;          // 2M x 4N waves
  const int q = lane & 15, hi = lane >> 4;
  const size_t ldb = (size_t)K * 2;           // row stride bytes

  f32x4 acc[8][4];
#pragma unroll
  for (int i = 0; i < 8; ++i)
#pragma unroll
    for (int j = 0; j < 4; ++j)
#pragma unroll
      for (int r = 0; r < 4; ++r) acc[i][j][r] = 0.f;

  // stage one K-tile (A 256x64 + B 256x64) into buf d; 8 glls, 1 KB/wave each
  auto STAGE = [&](int d, int kt) {
    const char* sA = (const char*)A + (size_t)m0 * ldb + kt * 128;
    const char* sB = (const char*)B + (size_t)n0 * ldb + kt * 128;
    char* dA = (char*)&lds[d][0][0];
    char* dB = (char*)&lds[d][1][0];
#pragma unroll
    for (int j = 0; j < 4; ++j) {
      int base = j * 8192 + w * 1024;
      int off = base + lane * 16;
      int row = off >> 7;                       // 128 B per LDS row
      int src = (off & 127) ^ ((row & 7) << 4); // pre-swizzled source
      GLL16(sA + (size_t)row * ldb + src, dA + base);
      GLL16(sB + (size_t)row * ldb + src, dB + base);
    }
  };
  auto LDA = [&](int d, int i, int ks) -> bf16x8 {
    int row = wm * 128 + i * 16 + q;
    int cb = ks * 64 + hi * 16;
    return *(const bf16x8*)((const char*)&lds[d][0][0] + row * 128 + (cb ^ ((row & 7) << 4)));
  };
  auto LDB = [&](int d, int j, int ks) -> bf16x8 {
    int row = wn * 64 + j * 16 + q;
    int cb = ks * 64 + hi * 16;
    return *(const bf16x8*)((const char*)&lds[d][1][0] + row * 128 + (cb ^ ((row & 7) << 4)));
  };

  // 4 phases over one K-tile in buf d: phase ph computes M_rep rows 2ph,2ph+1.
  // B-frags read once in phase 0, held in regs across phases.
  auto HALF = [&](int d) {
    bf16x8 bfr[4][2];
#pragma unroll
    for (int ph = 0; ph < 4; ++ph) {
      if (ph == 0) {
#pragma unroll
        for (int j = 0; j < 4; ++j)
#pragma unroll
          for (int ks = 0; ks < 2; ++ks) bfr[j][ks] = LDB(d, j, ks);
      }
      bf16x8 af[2][2];
#pragma unroll
      for (int m = 0; m < 2; ++m)
#pragma unroll
        for (int ks = 0; ks < 2; ++ks) af[m][ks] = LDA(d, 2 * ph + m, ks);
      __builtin_amdgcn_s_setprio(1);
#pragma unroll
      for (int m = 0; m < 2; ++m)
#pragma unroll
        for (int j = 0; j < 4; ++j)
#pragma unroll
          for (int ks = 0; ks < 2; ++ks)
            acc[2 * ph + m][j] = __builtin_amdgcn_mfma_f32_16x16x32_bf16(
                af[m][ks], bfr[j][ks], acc[2 * ph + m][j], 0, 0, 0);
      __builtin_amdgcn_s_setprio(0);
      if (ph < 3) BAR();
    }
  };

  const int NT2 = K >> 7;  // iterations; each covers 2 K-tiles (BK=64)
  STAGE(0, 0);
  STAGE(1, 1);
  VMC8();  // 16 outstanding -> wait until buf0's 8 landed (buf1 in flight)
  BAR();
  for (int t = 0; t < NT2; ++t) {
    HALF(0);               // reads buf0 (kt 2t); all reads consumed pre-barrier
    BAR();                 // buf0 dead for every wave
    if (t + 1 < NT2) { STAGE(0, 2 * t + 2); VMC8(); }  // older (buf1) landed
    else             VMC0();                            // drain: buf1 landed
    BAR();
    HALF(1);               // reads buf1 (kt 2t+1)
    BAR();                 // buf1 dead
    if (t + 1 < NT2) { STAGE(1, 2 * t + 3); VMC8(); }  // older (new buf0) landed
    else             VMC0();
    BAR();
  }

  // epilogue: row = m0 + wm*128 + i*16 + hi*4 + r,  col = n0 + wn*64 + j*16 + q
#pragma unroll
  for (int i = 0; i < 8; ++i) {
    int rbase = m0 + wm * 128 + i * 16 + (hi << 2);
#pragma unroll
    for (int j = 0; j < 4; ++j) {
      int col = n0 + wn * 64 + j * 16 + q;
      float bv = bias ? bias[col] : 0.f;
#pragma unroll
      for (int r = 0; r < 4; ++r) {
        int row = rbase + r;
        float v = acc[i][j][r] + bv;
        if (row < split) store_out(&Cenc[(size_t)row * N + col], v);
        else             store_out(&Cimg[(size_t)(row - split) * N + col], v);
      }
    }
  }
}

// ---------------- per-head RMSnorm(q,k) + RoPE(q,k), emit V^T -----------------
// Q pre-scaled by log2(e)/sqrt(128) so attn scores land in log2 units.
__global__ __launch_bounds__(256) void norm_rope(
    u16* __restrict__ qkv, u16* __restrict__ vt,
    const float* __restrict__ cosT, const float* __restrict__ sinT,
    const float* __restrict__ nqw_img, const float* __restrict__ nkw_img,
    const float* __restrict__ nqw_enc, const float* __restrict__ nkw_enc) {
  const int h = blockIdx.y;
  const int s0 = blockIdx.x * 64;
  const int tid = threadIdx.x, w = tid >> 6, lane = tid & 63;
  const bool enc = (s0 < 512);
  const float* nqw = enc ? nqw_enc : nqw_img;
  const float* nkw = enc ? nkw_enc : nkw_img;
  const float SCL = 0.12751743f;  // log2(e)/sqrt(128)
  const float wq0 = nqw[2 * lane], wq1 = nqw[2 * lane + 1];
  const float wk0 = nkw[2 * lane], wk1 = nkw[2 * lane + 1];
  u16x8 va0, va1, vb0, vb1;
#pragma unroll
  for (int r = 0; r < 16; ++r) {
    const int s = s0 + w * 16 + r;
    const size_t rowb = (size_t)s * 9216 + h * 128 + 2 * lane;
    float2 cv = *(const float2*)&cosT[(size_t)s * 128 + 2 * lane];
    float2 sv = *(const float2*)&sinT[(size_t)s * 128 + 2 * lane];
    {  // Q
      u16x2 qu = *(u16x2*)&qkv[rowb];
      float x0 = bf2f(qu.x), x1 = bf2f(qu.y);
      float ss = x0 * x0 + x1 * x1;
#pragma unroll
      for (int d = 1; d < 64; d <<= 1) ss += __shfl_xor(ss, d);
      float rms = rsqrtf(ss * (1.0f / 128.0f) + 1e-5f);
      x0 *= rms * wq0; x1 *= rms * wq1;
      float o0 = (x0 * cv.x - x1 * sv.x) * SCL;
      float o1 = (x1 * cv.y + x0 * sv.y) * SCL;
      u16x2 ou; ou.x = f2bf(o0); ou.y = f2bf(o1);
      *(u16x2*)&qkv[rowb] = ou;
    }
    {  // K
      u16x2 ku = *(u16x2*)&qkv[rowb + 3072];
      float x0 = bf2f(ku.x), x1 = bf2f(ku.y);
      float ss = x0 * x0 + x1 * x1;
#pragma unroll
      for (int d = 1; d < 64; d <<= 1) ss += __shfl_xor(ss, d);
      float rms = rsqrtf(ss * (1.0f / 128.0f) + 1e-5f);
      x0 *= rms * wk0; x1 *= rms * wk1;
      float o0 = x0 * cv.x - x1 * sv.x;
      float o1 = x1 * cv.y + x0 * sv.y;
      u16x2 ou; ou.x = f2bf(o0); ou.y = f2bf(o1);
      *(u16x2*)&qkv[rowb + 3072] = ou;
    }
    {  // V -> registers for transposed store
      u16x2 vu = *(u16x2*)&qkv[rowb + 6144];
      if (r < 8) { va0[r] = vu.x; vb0[r] = vu.y; }
      else       { va1[r - 8] = vu.x; vb1[r - 8] = vu.y; }
    }
  }
  const size_t vbase = (size_t)h * 128 * 3584 + (size_t)(2 * lane) * 3584 + s0 + w * 16;
  *(u16x8*)&vt[vbase]            = va0;
  *(u16x8*)&vt[vbase + 8]        = va1;
  *(u16x8*)&vt[vbase + 3584]     = vb0;
  *(u16x8*)&vt[vbase + 3584 + 8] = vb1;
}

// ---------------- flash attention ----------------
// 1-D grid 1344; (qt,h) decoded so each XCD gets 3 heads (K/V L2 locality).
// SWAPPED QK^T, defer-max, exp2 domain, setprio. See R5 notes.
__global__ __launch_bounds__(256, 4) void attn_kernel(
    const u16* __restrict__ qkv, const u16* __restrict__ vt,
    u16* __restrict__ aout) {
  const int bid = blockIdx.x;
  const int qt = bid / 24;
  const int rr = bid % 24;
  const int h = (rr % 8) * 3 + (rr / 8);   // bijective; clusters heads per XCD
  const int tid = threadIdx.x, w = tid >> 6, lane = tid & 63;
  const int qbase = qt * 64 + w * 16;
  const int q = lane & 15, hi = lane >> 4;
  __shared__ u16 Klds[64 * 128];
  __shared__ u16 Vlds[128 * 64];
  __shared__ u16 Plds[4][1024];

  bf16x8 aq[4];
  {
    const u16* qp = qkv + (size_t)(qbase + q) * 9216 + h * 128 + (hi << 3);
#pragma unroll
    for (int ks = 0; ks < 4; ++ks) aq[ks] = *(const bf16x8*)(qp + ks * 32);
  }
  float m_i = -1e30f, l_i = 0.f;
  f32x4 o[8];
#pragma unroll
  for (int dt = 0; dt < 8; ++dt)
#pragma unroll
    for (int r = 0; r < 4; ++r) o[dt][r] = 0.f;
  const size_t vhead = (size_t)h * 128 * 3584;

  for (int kt0 = 0; kt0 < 3584; kt0 += 64) {
    __syncthreads();
#pragma unroll
    for (int j = 0; j < 4; ++j) {  // K tile: 64 rows x 256B
      int base = w * 4096 + j * 1024;
      int off = base + lane * 16;
      int row = off >> 8;
      int src = (off & 255) ^ ((row & 7) << 4);
      GLL16((const char*)(qkv + (size_t)(kt0 + row) * 9216 + 3072 + h * 128) + src, (char*)Klds + base);
    }
#pragma unroll
    for (int j = 0; j < 4; ++j) {  // V^T tile: 128 rows x 128B
      int base = w * 4096 + j * 1024;
      int off = base + lane * 16;
      int d = off >> 7;
      int src = (off & 127) ^ ((d & 7) << 4);
      GLL16((const char*)(vt + vhead + (size_t)d * 3584 + kt0) + src, (char*)Vlds + base);
    }
    __syncthreads();

    // S^T = K Q^T (swapped operands; log2 units via pre-scaled Q)
    f32x4 sacc[4];
#pragma unroll
    for (int kt = 0; kt < 4; ++kt)
#pragma unroll
      for (int r = 0; r < 4; ++r) sacc[kt][r] = 0.f;
    __builtin_amdgcn_s_setprio(1);
#pragma unroll
    for (int kt = 0; kt < 4; ++kt) {
      const int row = kt * 16 + q;
      bf16x8 bk[4];
#pragma unroll
      for (int ks = 0; ks < 4; ++ks) {
        int cb = (ks * 32 + (hi << 3)) * 2;
        bk[ks] = *(const bf16x8*)((const char*)Klds + (row * 256 + (cb ^ ((row & 7) << 4))));
      }
#pragma unroll
      for (int ks = 0; ks < 4; ++ks)
        sacc[kt] = __builtin_amdgcn_mfma_f32_16x16x32_bf16(bk[ks], aq[ks], sacc[kt], 0, 0, 0);
    }
    __builtin_amdgcn_s_setprio(0);

    float mx = sacc[0][0];
#pragma unroll
    for (int kt = 0; kt < 4; ++kt)
#pragma unroll
      for (int r = 0; r < 4; ++r) mx = fmaxf(mx, sacc[kt][r]);
    mx = fmaxf(mx, __shfl_xor(mx, 16));
    mx = fmaxf(mx, __shfl_xor(mx, 32));
    if (!__all(mx - m_i <= 8.f)) {
      float mnew = fmaxf(m_i, mx);
      float alpha = __builtin_amdgcn_exp2f(m_i - mnew);
      m_i = mnew;
      l_i *= alpha;
#pragma unroll
      for (int r = 0; r < 4; ++r) {
        float ar = __shfl(alpha, (lane & 48) | ((hi << 2) + r));
#pragma unroll
        for (int dt = 0; dt < 8; ++dt) o[dt][r] *= ar;
      }
    }
    float psum = 0.f;
#pragma unroll
    for (int kt = 0; kt < 4; ++kt) {
      u16x4 pw;
#pragma unroll
      for (int r = 0; r < 4; ++r) {
        float p = __builtin_amdgcn_exp2f(sacc[kt][r] - m_i);
        psum += p;
        pw[r] = (u16)(__builtin_bit_cast(unsigned, p) >> 16);  // trunc bf16
      }
      *(u16x4*)((char*)Plds[w] + ((q * 128 + kt * 32 + hi * 8) ^ ((q & 7) << 4))) = pw;
    }
    psum += __shfl_xor(psum, 16);
    psum += __shfl_xor(psum, 32);
    l_i += psum;

    bf16x8 pa[2];
#pragma unroll
    for (int ks = 0; ks < 2; ++ks) {
      int cb = (ks * 32 + (hi << 3)) * 2;
      pa[ks] = *(const bf16x8*)((const char*)Plds[w] + ((q * 128 + cb) ^ ((q & 7) << 4)));
    }
    __builtin_amdgcn_s_setprio(1);
#pragma unroll
    for (int dt = 0; dt < 8; ++dt) {
      const int vrow = dt * 16 + q;
      bf16x8 bv[2];
#pragma unroll
      for (int ks = 0; ks < 2; ++ks) {
        int cb = (ks * 32 + (hi << 3)) * 2;
        bv[ks] = *(const bf16x8*)((const char*)Vlds + ((vrow * 128 + cb) ^ ((vrow & 7) << 4)));
      }
      o[dt] = __builtin_amdgcn_mfma_f32_16x16x32_bf16(pa[0], bv[0], o[dt], 0, 0, 0);
      o[dt] = __builtin_amdgcn_mfma_f32_16x16x32_bf16(pa[1], bv[1], o[dt], 0, 0, 0);
    }
    __builtin_amdgcn_s_setprio(0);
  }

#pragma unroll
  for (int r = 0; r < 4; ++r) {
    const int q2 = (hi << 2) + r;
    const float lr = __shfl(l_i, (lane & 48) | q2);
    const float inv = 1.0f / lr;
    const int s = qbase + q2;
#pragma unroll
    for (int dt = 0; dt < 8; ++dt) {
      aout[(size_t)s * 3072 + h * 128 + dt * 16 + q] = f2bf(o[dt][r] * inv);
    }
  }
}

extern "C" void kernel_launch(void* const* d_in, const int* in_sizes, int n_in,
                              void* d_out, int out_size, void* d_ws, size_t ws_size,
                              hipStream_t stream) {
  (void)in_sizes; (void)n_in; (void)out_size; (void)ws_size;
  const float* hs    = (const float*)d_in[0];
  const float* ehs   = (const float*)d_in[1];
  const float* cosT  = (const float*)d_in[2];
  const float* sinT  = (const float*)d_in[3];
  const float* Wqkv  = (const float*)d_in[4];
  const float* Wadd  = (const float*)d_in[5];
  const float* bAdd  = (const float*)d_in[6];
  const float* nqw   = (const float*)d_in[7];
  const float* nkw   = (const float*)d_in[8];
  const float* naqw  = (const float*)d_in[9];
  const float* nakw  = (const float*)d_in[10];
  const float* Wout  = (const float*)d_in[11];
  const float* bout  = (const float*)d_in[12];
  const float* Waddo = (const float*)d_in[13];
  const float* baddo = (const float*)d_in[14];

  char* ws = (char*)d_ws;
  u16* Ain = (u16*)(ws);                       // [3584][3072]
  u16* WqI = (u16*)(ws + 22020096);            // [9216][3072]
  u16* WqE = WqI + (size_t)9216 * 3072;
  u16* WoI = (u16*)(ws + 135266304);           // [3072][3072]
  u16* WoE = WoI + (size_t)3072 * 3072;
  u16* qkv = (u16*)(ws + 173015040);           // [3584][9216]
  u16* vt   = Ain;  // alias: A_in dead after QKV GEMM
  u16* aout = WqI;  // alias: W_qkv dead after QKV GEMM

  cvt_kernel<<<1024, 256, 0, stream>>>(ehs,   Ain,                      512 * 3072 / 4);
  cvt_kernel<<<1024, 256, 0, stream>>>(hs,    Ain + (size_t)512 * 3072, 3072 * 3072 / 4);
  cvt_kernel<<<2048, 256, 0, stream>>>(Wqkv,  WqI, 9216 * 3072 / 4);
  cvt_kernel<<<2048, 256, 0, stream>>>(Wadd,  WqE, 9216 * 3072 / 4);
  cvt_kernel<<<1024, 256, 0, stream>>>(Wout,  WoI, 3072 * 3072 / 4);
  cvt_kernel<<<1024, 256, 0, stream>>>(Waddo, WoE, 3072 * 3072 / 4);

  // QKV: [3584][9216] = A_in x W^T (+ bias on enc rows), bf16 out (internal)
  gemm256<u16><<<dim3(504), 512, 0, stream>>>(Ain, WqI, WqE, nullptr, bAdd,
                                              qkv + (size_t)512 * 9216, qkv, 9216, 3072, 512, 504);
  norm_rope<<<dim3(56, 24), 256, 0, stream>>>(qkv, vt, cosT, sinT, nqw, nkw, naqw, nakw);
  attn_kernel<<<dim3(1344), 256, 0, stream>>>(qkv, vt, aout);
  // out proj: FLOAT32 output — img rows -> d_out[0:3072*3072], enc rows after
  float* outp = (float*)d_out;
  gemm256<float><<<dim3(168), 512, 0, stream>>>(aout, WoI, WoE, bout, baddo,
                                                outp, outp + (size_t)3072 * 3072, 3072, 3072, 512, 168);
}